// Round 16
// baseline (70.678 us; speedup 1.0000x reference)
//
#include <hip/hip_runtime.h>

#define HW 2304
#define WID 48

typedef __attribute__((ext_vector_type(8))) short bf16x8;
typedef __attribute__((ext_vector_type(4))) float f32x4;
typedef __attribute__((ext_vector_type(2))) _Float16 half2v;

__device__ __forceinline__ half2v pk_h2(float lo, float hi) {
  return __builtin_bit_cast(half2v, __builtin_amdgcn_cvt_pkrtz(lo, hi));
}

__device__ __forceinline__ unsigned pack_bf2(float lo, float hi) {
  unsigned a = __builtin_bit_cast(unsigned, lo);
  unsigned b = __builtin_bit_cast(unsigned, hi);
  a = (a + 0x7FFFu + ((a >> 16) & 1u)) >> 16;
  b = (b + 0x7FFFu + ((b >> 16) & 1u)) >> 16;
  return a | (b << 16);
}
__device__ __forceinline__ unsigned short bf16_of(float x) {
  unsigned u = __builtin_bit_cast(unsigned, x);
  u = (u + 0x7FFFu + ((u >> 16) & 1u)) >> 16;
  return (unsigned short)u;
}
__device__ __forceinline__ unsigned short f16_of(float x) {
  _Float16 h = (_Float16)x;
  return __builtin_bit_cast(unsigned short, h);
}

// ---------------- Weight prep: fp32 [N][K] -> fragment-ordered bf16
__global__ __launch_bounds__(256) void prep_w(
    const float* __restrict__ wq, const float* __restrict__ wk,
    const float* __restrict__ wv, const float* __restrict__ w1,
    const float* __restrict__ w2, unsigned* __restrict__ wf)
{
  int fid = blockIdx.x * 4 + (threadIdx.x >> 6);
  int l = threadIdx.x & 63;
  const float* src; int K; int base;
  if (fid < 72)       { src = wq; K = 192; base = 0; }
  else if (fid < 144) { src = wk; K = 192; base = 72; }
  else if (fid < 216) { src = wv; K = 192; base = 144; }
  else if (fid < 360) { src = w1; K = 192; base = 216; }
  else                { src = w2; K = 384; base = 360; }
  int local = fid - base;
  int KS = K / 32;
  int nf = local / KS, ks = local % KS;
  int row = nf * 16 + (l & 15);
  int c0 = ks * 32 + (l >> 4) * 8;
  const float* p = src + (size_t)row * K + c0;
  float4 v0 = *(const float4*)p;
  float4 v1 = *(const float4*)(p + 4);
  unsigned* dst = wf + ((size_t)fid * 64 + l) * 4;
  dst[0] = pack_bf2(v0.x, v0.y);
  dst[1] = pack_bf2(v0.z, v0.w);
  dst[2] = pack_bf2(v1.x, v1.y);
  dst[3] = pack_bf2(v1.z, v1.w);
}

// ---------------- Projection via MFMA. q slab -> fp32 qp [B][HW][192];
// k/v slabs -> f16 kvp [bc][kv][pk(6)][HW][32ch] (64B per pixel-headpair entry)
__global__ __launch_bounds__(256) void proj_mfma(
    const float* __restrict__ q, const float* __restrict__ k, const float* __restrict__ v,
    const unsigned* __restrict__ wf,
    const float* __restrict__ bq, const float* __restrict__ bk, const float* __restrict__ bv,
    float* __restrict__ qp, unsigned short* __restrict__ kvp)
{
  __shared__ unsigned lds[64 * 100];
  int slab = blockIdx.y;
  const float* in; const unsigned* wfr; const float* bias;
  float* outf = nullptr; unsigned short* outh = nullptr;
  if (slab < 4) {
    in = q + (size_t)slab * 192 * HW; wfr = wf; bias = bq;
    outf = qp + (size_t)slab * HW * 192;
  } else if (slab < 12) {
    int c = slab - 4;
    in = k + (size_t)c * 192 * HW; wfr = wf + 72 * 256; bias = bk;
    outh = kvp + (size_t)c * 2 * 6 * HW * 32;            // kv=0
  } else {
    int c = slab - 12;
    in = v + (size_t)c * 192 * HW; wfr = wf + 144 * 256; bias = bv;
    outh = kvp + ((size_t)c * 2 + 1) * 6 * HW * 32;      // kv=1
  }
  const int n0 = blockIdx.x * 64;
  const int t = threadIdx.x;
  const int w = t >> 6, l = t & 63;

  {
    int pix = t & 63;
    int cp0 = t >> 6;
    const float* s0 = in + n0 + pix;
#pragma unroll
    for (int i = 0; i < 24; ++i) {
      int cp = cp0 * 24 + i;
      float lo = s0[(size_t)(2 * cp) * HW];
      float hi = s0[(size_t)(2 * cp + 1) * HW];
      lds[pix * 100 + cp] = pack_bf2(lo, hi);
    }
  }

  bf16x8 wfrag[6][3];
#pragma unroll
  for (int ks = 0; ks < 6; ++ks)
#pragma unroll
    for (int nfi = 0; nfi < 3; ++nfi) {
      int nf = w * 3 + nfi;
      wfrag[ks][nfi] = ((const bf16x8*)wfr)[(nf * 6 + ks) * 64 + l];
    }

  __syncthreads();

  f32x4 acc[3][4];
#pragma unroll
  for (int a = 0; a < 3; ++a)
#pragma unroll
    for (int m = 0; m < 4; ++m) acc[a][m] = (f32x4){0.f, 0.f, 0.f, 0.f};

#pragma unroll
  for (int ks = 0; ks < 6; ++ks) {
    bf16x8 af[4];
#pragma unroll
    for (int mf = 0; mf < 4; ++mf)
      af[mf] = *(const bf16x8*)&lds[(mf * 16 + (l & 15)) * 100 + ks * 16 + (l >> 4) * 4];
#pragma unroll
    for (int nfi = 0; nfi < 3; ++nfi)
#pragma unroll
      for (int mf = 0; mf < 4; ++mf)
        acc[nfi][mf] = __builtin_amdgcn_mfma_f32_16x16x32_bf16(af[mf], wfrag[ks][nfi], acc[nfi][mf], 0, 0, 0);
  }

#pragma unroll
  for (int nfi = 0; nfi < 3; ++nfi) {
    int oc = (w * 3 + nfi) * 16 + (l & 15);
    float bs = bias[oc];
    if (outf) {
#pragma unroll
      for (int mf = 0; mf < 4; ++mf) {
        int pixb = n0 + mf * 16 + (l >> 4) * 4;
#pragma unroll
        for (int j = 0; j < 4; ++j)
          outf[(size_t)(pixb + j) * 192 + oc] = acc[nfi][mf][j] + bs;
      }
    } else {
      int pkh = oc >> 5, ch = oc & 31;
#pragma unroll
      for (int mf = 0; mf < 4; ++mf) {
        int pixb = n0 + mf * 16 + (l >> 4) * 4;
#pragma unroll
        for (int j = 0; j < 4; ++j)
          outh[((size_t)pkh * HW + pixb + j) * 32 + ch] = f16_of(acc[nfi][mf][j] + bs);
      }
    }
  }
}

// ---------------- Deformable attention, clip-split partials.
// block = (b, half, clip, head-pair, 32-pixel tile); grid = 3456 (2x threads).
// Emits exact flash-style partials {PV[32], m0,Z0,m1,Z1} per (pixel, head-pair).
// opart layout: [clip(2)][b(4)][pk(6)][HW][36 floats]
__global__ __launch_bounds__(256, 4) void attn_part(
    const float* __restrict__ qp, const unsigned short* __restrict__ kvp,
    const float* __restrict__ offs, float* __restrict__ opart)
{
  __shared__ uint4 rec[2][9][32];   // [dgsel][tap][pix] for this block's clip
  const int t = threadIdx.x;
  const int g = blockIdx.x & 7;          // (b, half) -> XCD-resident KV slab
  const int pos = blockIdx.x >> 3;       // 0..431
  const int b = g >> 1;
  const int half = g & 1;
  const int clip = pos / 216;
  const int r2 = pos % 216;
  const int pk = r2 / 36;
  const int tile = r2 % 36;
  const int n_base = half * 1152 + tile * 32;
  const int bc = b * 2 + clip;

  // ---- in-block record computation: 576 records, 2.25 per thread
#pragma unroll
  for (int i = 0; i < 3; ++i) {
    int rid = t + i * 256;
    if (rid < 576) {
      int rpix = rid & 31;
      int rest = rid >> 5;               // 0..17 = (dgsel, tap)
      int rtap = rest % 9;
      int dgsel = rest / 9;
      int rn = n_base + rpix;
      int rh = rn / WID, rw = rn % WID;
      int dg = pk + dgsel * 6;
      const float* ob = offs + ((size_t)bc * 216 + (size_t)(dg * 9 + rtap) * 2) * HW + rn;
      float oy = ob[0];
      float ox = ob[HW];
      float py = (float)(rh - 1 + rtap / 3) + oy;
      float px = (float)(rw - 1 + rtap % 3) + ox;
      float y0f = floorf(py), x0f = floorf(px);
      int y0 = (int)y0f, x0 = (int)x0f;
      float wy1 = py - y0f, wx1 = px - x0f;
      float wy0 = 1.f - wy1, wx0 = 1.f - wx1;
      unsigned ip[2];
      float wv[4];
#pragma unroll
      for (int cy = 0; cy < 2; ++cy) {
        int yi = y0 + cy;
        float wyv = cy ? wy1 : wy0;
        int yc = yi < 0 ? 0 : (yi > 47 ? 47 : yi);
        bool vy = (unsigned)yi < 48u;
#pragma unroll
        for (int cx = 0; cx < 2; ++cx) {
          int xi = x0 + cx;
          float wxv = cx ? wx1 : wx0;
          int xc = xi < 0 ? 0 : (xi > 47 ? 47 : xi);
          bool vx = (unsigned)xi < 48u;
          float wgt = (vy && vx) ? wyv * wxv : 0.f;
          int ci = cy * 2 + cx;
          wv[ci] = wgt;
          ((unsigned short*)ip)[ci] = (unsigned short)(yc * WID + xc);
        }
      }
      uint4 rc;
      rc.x = ip[0];
      rc.y = ip[1];
      rc.z = __builtin_bit_cast(unsigned, pk_h2(wv[0], wv[1]));
      rc.w = __builtin_bit_cast(unsigned, pk_h2(wv[2], wv[3]));
      rec[dgsel][rtap][rpix] = rc;
    }
  }

  const int l8 = t & 7;
  const int csel = l8 >> 2;      // corner slot: 0 -> A/C, 1 -> B/D
  const int chq = l8 & 3;        // 8-channel quarter within the 32-ch head-pair
  const int pix = t >> 3;
  const int n = n_base + pix;

  // q: 8 channels for this lane's quarter
  half2v qh[4];
  {
    const float* qb = qp + ((size_t)b * HW + n) * 192 + pk * 32 + chq * 8;
    float4 v0 = *(const float4*)qb;
    float4 v1 = *(const float4*)(qb + 4);
    qh[0] = pk_h2(v0.x * 0.25f, v0.y * 0.25f);
    qh[1] = pk_h2(v0.z * 0.25f, v0.w * 0.25f);
    qh[2] = pk_h2(v1.x * 0.25f, v1.y * 0.25f);
    qh[3] = pk_h2(v1.z * 0.25f, v1.w * 0.25f);
  }

  __syncthreads();

  float sc[9];

  // ---- K phase: dense [HW][32] plane for (bc, k, pk); pure load+fdot body
  {
    const unsigned short* kb = kvp + (((size_t)bc * 2 + 0) * 6 + pk) * HW * 32 + chq * 8;
#pragma unroll
    for (int kk = 0; kk < 9; ++kk) {
      uint4 rc = rec[0][kk][pix];
      float s = 0.f;
#pragma unroll
      for (int r = 0; r < 2; ++r) {
        unsigned pr = r ? rc.y : rc.x;
        unsigned idx = csel ? (pr >> 16) : (pr & 0xFFFFu);
        half2v wp = __builtin_bit_cast(half2v, r ? rc.w : rc.z);
        _Float16 wh = csel ? wp.y : wp.x;
        uint4 u = *(const uint4*)(kb + (size_t)idx * 32);
        float d = __builtin_amdgcn_fdot2(qh[0], __builtin_bit_cast(half2v, u.x), 0.f, false);
        d = __builtin_amdgcn_fdot2(qh[1], __builtin_bit_cast(half2v, u.y), d, false);
        d = __builtin_amdgcn_fdot2(qh[2], __builtin_bit_cast(half2v, u.z), d, false);
        d = __builtin_amdgcn_fdot2(qh[3], __builtin_bit_cast(half2v, u.w), d, false);
        s += (float)wh * d;
      }
      sc[kk] = s;
    }
  }

  // ---- batched cross-lane reduction: per-head score in every lane
#pragma unroll
  for (int j = 0; j < 9; ++j) sc[j] += __shfl_xor(sc[j], 1, 64);
#pragma unroll
  for (int j = 0; j < 9; ++j) sc[j] += __shfl_xor(sc[j], 4, 64);

  // ---- partial softmax over this clip's 9 taps
  float m = -1e30f;
#pragma unroll
  for (int j = 0; j < 9; ++j) m = fmaxf(m, sc[j]);
  float Z = 0.f;
#pragma unroll
  for (int j = 0; j < 9; ++j) { float ev = __expf(sc[j] - m); sc[j] = ev; Z += ev; }

  // ---- V phase: unnormalized exp-weighted accumulation
  float acc[8];
#pragma unroll
  for (int i = 0; i < 8; ++i) acc[i] = 0.f;
  {
    const unsigned short* vb = kvp + (((size_t)bc * 2 + 1) * 6 + pk) * HW * 32 + chq * 8;
#pragma unroll
    for (int kk = 0; kk < 9; ++kk) {
      uint4 rc = rec[1][kk][pix];
      float at = sc[kk];
#pragma unroll
      for (int r = 0; r < 2; ++r) {
        unsigned pr = r ? rc.y : rc.x;
        unsigned idx = csel ? (pr >> 16) : (pr & 0xFFFFu);
        half2v wp = __builtin_bit_cast(half2v, r ? rc.w : rc.z);
        _Float16 wh = csel ? wp.y : wp.x;
        uint4 u = *(const uint4*)(vb + (size_t)idx * 32);
        float cw = (float)wh * at;
        half2v v0 = __builtin_bit_cast(half2v, u.x);
        half2v v1 = __builtin_bit_cast(half2v, u.y);
        half2v v2 = __builtin_bit_cast(half2v, u.z);
        half2v v3 = __builtin_bit_cast(half2v, u.w);
        acc[0] += cw * (float)v0.x; acc[1] += cw * (float)v0.y;
        acc[2] += cw * (float)v1.x; acc[3] += cw * (float)v1.y;
        acc[4] += cw * (float)v2.x; acc[5] += cw * (float)v2.y;
        acc[6] += cw * (float)v3.x; acc[7] += cw * (float)v3.y;
      }
    }
  }

  // cross-corner-lane reduce (lane ^ 4 holds the other corner slot)
#pragma unroll
  for (int i = 0; i < 8; ++i) acc[i] += __shfl_xor(acc[i], 4, 64);

  if (csel == 0) {
    float* obase = opart + ((((size_t)clip * 4 + b) * 6 + pk) * HW + n) * 36;
    float4 r0; r0.x = acc[0]; r0.y = acc[1]; r0.z = acc[2]; r0.w = acc[3];
    float4 r1; r1.x = acc[4]; r1.y = acc[5]; r1.z = acc[6]; r1.w = acc[7];
    *(float4*)(obase + chq * 8) = r0;
    *(float4*)(obase + chq * 8 + 4) = r1;
    if (chq == 0) { obase[32] = m; obase[33] = Z; }
    if (chq == 2) { obase[34] = m; obase[35] = Z; }
  }
}

// ---------------- Exact flash-style clip combination -> o_ws [B][HW][192]
__global__ __launch_bounds__(256) void attn_combine(
    const float* __restrict__ opart, float* __restrict__ o_ws)
{
  int gid = blockIdx.x * 256 + threadIdx.x;   // < 4*6*2304*4
  int chq = gid & 3;
  int e = gid >> 2;
  int n = e % HW;
  int r = e / HW;
  int pk = r % 6;
  int b = r / 6;
  const float* pa = opart + (((size_t)(b * 6 + pk)) * HW + n) * 36;
  const float* pb = pa + (size_t)24 * HW * 36;
  int hsel = chq >> 1;
  float ma = pa[32 + 2 * hsel], za = pa[33 + 2 * hsel];
  float mb = pb[32 + 2 * hsel], zb = pb[33 + 2 * hsel];
  float m = fmaxf(ma, mb);
  float sa = __expf(ma - m), sb = __expf(mb - m);
  float inv = 1.f / (za * sa + zb * sb);
  float4 a0 = *(const float4*)(pa + chq * 8);
  float4 a1 = *(const float4*)(pa + chq * 8 + 4);
  float4 b0 = *(const float4*)(pb + chq * 8);
  float4 b1 = *(const float4*)(pb + chq * 8 + 4);
  float* o = o_ws + ((size_t)b * HW + n) * 192 + pk * 32 + chq * 8;
  float4 r0, r1;
  r0.x = (a0.x * sa + b0.x * sb) * inv; r0.y = (a0.y * sa + b0.y * sb) * inv;
  r0.z = (a0.z * sa + b0.z * sb) * inv; r0.w = (a0.w * sa + b0.w * sb) * inv;
  r1.x = (a1.x * sa + b1.x * sb) * inv; r1.y = (a1.y * sa + b1.y * sb) * inv;
  r1.z = (a1.z * sa + b1.z * sb) * inv; r1.w = (a1.w * sa + b1.w * sb) * inv;
  *(float4*)o = r0;
  *(float4*)(o + 4) = r1;
}

// ---------------- MLP via MFMA: one block per 16-pixel tile
__global__ __launch_bounds__(256) void mlp_mfma(
    const float* __restrict__ o_ws, const unsigned* __restrict__ wf,
    const float* __restrict__ b1, const float* __restrict__ b2,
    float* __restrict__ out)
{
  __shared__ unsigned ldsO[16 * 100];
  __shared__ unsigned ldsH[16 * 196];
  const unsigned* w1f = wf + 216 * 256;
  const unsigned* w2f = wf + 360 * 256;
  const int blk = blockIdx.x;
  const int b = blk / 144;
  const int n0 = (blk % 144) * 16;
  const int t = threadIdx.x;
  const int w = t >> 6, l = t & 63;

  for (int i = t; i < 16 * 96; i += 256) {
    int pix = i / 96, cp = i % 96;
    const float2 s = *(const float2*)(o_ws + ((size_t)(b * HW) + n0 + pix) * 192 + 2 * cp);
    ldsO[pix * 100 + cp] = pack_bf2(s.x, s.y);
  }
  __syncthreads();

  f32x4 acc1[6];
#pragma unroll
  for (int a = 0; a < 6; ++a) acc1[a] = (f32x4){0.f, 0.f, 0.f, 0.f};
#pragma unroll
  for (int ks = 0; ks < 6; ++ks) {
    bf16x8 af = *(const bf16x8*)&ldsO[(l & 15) * 100 + ks * 16 + (l >> 4) * 4];
#pragma unroll
    for (int nfi = 0; nfi < 6; ++nfi) {
      int nf = w * 6 + nfi;
      bf16x8 bfr = ((const bf16x8*)w1f)[(nf * 6 + ks) * 64 + l];
      acc1[nfi] = __builtin_amdgcn_mfma_f32_16x16x32_bf16(af, bfr, acc1[nfi], 0, 0, 0);
    }
  }

  {
    unsigned short* ldsHu = (unsigned short*)ldsH;
#pragma unroll
    for (int nfi = 0; nfi < 6; ++nfi) {
      int hc = (w * 6 + nfi) * 16 + (l & 15);
      float bs = b1[hc];
#pragma unroll
      for (int j = 0; j < 4; ++j) {
        int pix = (l >> 4) * 4 + j;
        float x = acc1[nfi][j] + bs;
        float gl = 0.5f * x * (1.f + erff(x * 0.70710678118654752f));
        ldsHu[pix * 392 + hc] = bf16_of(gl);
      }
    }
  }
  __syncthreads();

  f32x4 acc2[3];
#pragma unroll
  for (int a = 0; a < 3; ++a) acc2[a] = (f32x4){0.f, 0.f, 0.f, 0.f};
#pragma unroll
  for (int ks = 0; ks < 12; ++ks) {
    bf16x8 af = *(const bf16x8*)&ldsH[(l & 15) * 196 + ks * 16 + (l >> 4) * 4];
#pragma unroll
    for (int nfi = 0; nfi < 3; ++nfi) {
      int nf = w * 3 + nfi;
      bf16x8 bfr = ((const bf16x8*)w2f)[(nf * 12 + ks) * 64 + l];
      acc2[nfi] = __builtin_amdgcn_mfma_f32_16x16x32_bf16(af, bfr, acc2[nfi], 0, 0, 0);
    }
  }

#pragma unroll
  for (int nfi = 0; nfi < 3; ++nfi) {
    int oc = (w * 3 + nfi) * 16 + (l & 15);
    float bs = b2[oc];
#pragma unroll
    for (int j = 0; j < 4; ++j) {
      int pix = (l >> 4) * 4 + j;
      float res = o_ws[((size_t)(b * HW) + n0 + pix) * 192 + oc];
      out[((size_t)b * 192 + oc) * HW + n0 + pix] = acc2[nfi][j] + bs + res;
    }
  }
}

extern "C" void kernel_launch(void* const* d_in, const int* in_sizes, int n_in,
                              void* d_out, int out_size, void* d_ws, size_t ws_size,
                              hipStream_t stream) {
  const float* q = (const float*)d_in[0];
  const float* k = (const float*)d_in[1];
  const float* v = (const float*)d_in[2];
  const float* offset = (const float*)d_in[3];
  const float* wq = (const float*)d_in[4];
  const float* bq = (const float*)d_in[5];
  const float* wk = (const float*)d_in[6];
  const float* bk = (const float*)d_in[7];
  const float* wv = (const float*)d_in[8];
  const float* bv = (const float*)d_in[9];
  const float* w1 = (const float*)d_in[10];
  const float* b1 = (const float*)d_in[11];
  const float* w2 = (const float*)d_in[12];
  const float* b2 = (const float*)d_in[13];
  float* out = (float*)d_out;

  float* qp_t = (float*)d_ws;                                    // 4*2304*192 f32
  float* o_ws = qp_t + (size_t)4 * HW * 192;                     // 4*2304*192 f32
  unsigned short* kvp = (unsigned short*)(o_ws + (size_t)4 * HW * 192);  // 8*2*6*2304*32 u16
  unsigned* wfb = (unsigned*)(kvp + (size_t)8 * 2 * 6 * HW * 32);        // 504*256 u32
  float* opart = (float*)(wfb + 504 * 256);                      // 2*4*6*2304*36 f32

  prep_w<<<dim3(126), dim3(256), 0, stream>>>(wq, wk, wv, w1, w2, wfb);
  proj_mfma<<<dim3(36, 20), dim3(256), 0, stream>>>(q, k, v, wfb, bq, bk, bv, qp_t, kvp);
  attn_part<<<dim3(3456), dim3(256), 0, stream>>>(qp_t, kvp, offset, opart);
  attn_combine<<<dim3(864), dim3(256), 0, stream>>>(opart, o_ws);
  mlp_mfma<<<dim3(576), dim3(256), 0, stream>>>(o_ws, wfb, b1, b2, out);
}

// Round 17
// 66.197 us; speedup vs baseline: 1.0677x; 1.0677x over previous
//
#include <hip/hip_runtime.h>

#define HW 2304
#define WID 48

typedef __attribute__((ext_vector_type(8))) short bf16x8;
typedef __attribute__((ext_vector_type(4))) float f32x4;
typedef __attribute__((ext_vector_type(2))) _Float16 half2v;

__device__ __forceinline__ half2v pk_h2(float lo, float hi) {
  return __builtin_bit_cast(half2v, __builtin_amdgcn_cvt_pkrtz(lo, hi));
}

__device__ __forceinline__ unsigned pack_bf2(float lo, float hi) {
  unsigned a = __builtin_bit_cast(unsigned, lo);
  unsigned b = __builtin_bit_cast(unsigned, hi);
  a = (a + 0x7FFFu + ((a >> 16) & 1u)) >> 16;
  b = (b + 0x7FFFu + ((b >> 16) & 1u)) >> 16;
  return a | (b << 16);
}
__device__ __forceinline__ unsigned short bf16_of(float x) {
  unsigned u = __builtin_bit_cast(unsigned, x);
  u = (u + 0x7FFFu + ((u >> 16) & 1u)) >> 16;
  return (unsigned short)u;
}
__device__ __forceinline__ unsigned short f16_of(float x) {
  _Float16 h = (_Float16)x;
  return __builtin_bit_cast(unsigned short, h);
}

// ---------------- Weight prep: fp32 [N][K] -> fragment-ordered bf16
__global__ __launch_bounds__(256) void prep_w(
    const float* __restrict__ wq, const float* __restrict__ wk,
    const float* __restrict__ wv, const float* __restrict__ w1,
    const float* __restrict__ w2, unsigned* __restrict__ wf)
{
  int fid = blockIdx.x * 4 + (threadIdx.x >> 6);
  int l = threadIdx.x & 63;
  const float* src; int K; int base;
  if (fid < 72)       { src = wq; K = 192; base = 0; }
  else if (fid < 144) { src = wk; K = 192; base = 72; }
  else if (fid < 216) { src = wv; K = 192; base = 144; }
  else if (fid < 360) { src = w1; K = 192; base = 216; }
  else                { src = w2; K = 384; base = 360; }
  int local = fid - base;
  int KS = K / 32;
  int nf = local / KS, ks = local % KS;
  int row = nf * 16 + (l & 15);
  int c0 = ks * 32 + (l >> 4) * 8;
  const float* p = src + (size_t)row * K + c0;
  float4 v0 = *(const float4*)p;
  float4 v1 = *(const float4*)(p + 4);
  unsigned* dst = wf + ((size_t)fid * 64 + l) * 4;
  dst[0] = pack_bf2(v0.x, v0.y);
  dst[1] = pack_bf2(v0.z, v0.w);
  dst[2] = pack_bf2(v1.x, v1.y);
  dst[3] = pack_bf2(v1.z, v1.w);
}

// ---------------- Projection via MFMA. q slab -> fp32 qp [B][HW][192];
// k/v slabs -> f16 kvp [bc][kv][pk(6)][HW][32ch] (64B per pixel-headpair entry)
// Staging vectorized: float4 along n (12 loads/thread), transpose via ds_write_b16.
__global__ __launch_bounds__(256) void proj_mfma(
    const float* __restrict__ q, const float* __restrict__ k, const float* __restrict__ v,
    const unsigned* __restrict__ wf,
    const float* __restrict__ bq, const float* __restrict__ bk, const float* __restrict__ bv,
    float* __restrict__ qp, unsigned short* __restrict__ kvp)
{
  __shared__ unsigned lds[64 * 100];
  int slab = blockIdx.y;
  const float* in; const unsigned* wfr; const float* bias;
  float* outf = nullptr; unsigned short* outh = nullptr;
  if (slab < 4) {
    in = q + (size_t)slab * 192 * HW; wfr = wf; bias = bq;
    outf = qp + (size_t)slab * HW * 192;
  } else if (slab < 12) {
    int c = slab - 4;
    in = k + (size_t)c * 192 * HW; wfr = wf + 72 * 256; bias = bk;
    outh = kvp + (size_t)c * 2 * 6 * HW * 32;            // kv=0
  } else {
    int c = slab - 12;
    in = v + (size_t)c * 192 * HW; wfr = wf + 144 * 256; bias = bv;
    outh = kvp + ((size_t)c * 2 + 1) * 6 * HW * 32;      // kv=1
  }
  const int n0 = blockIdx.x * 64;
  const int t = threadIdx.x;
  const int w = t >> 6, l = t & 63;

  // stage: thread (g4 = 4-pixel group, cb = channel block) loads float4 along n
  {
    int g4 = t & 15;
    int cb = t >> 4;
    unsigned short* lds16 = (unsigned short*)lds;
#pragma unroll
    for (int j = 0; j < 12; ++j) {
      int c = cb + j * 16;
      float4 vv = *(const float4*)(in + (size_t)c * HW + n0 + g4 * 4);
      lds16[(g4 * 4 + 0) * 200 + c] = bf16_of(vv.x);
      lds16[(g4 * 4 + 1) * 200 + c] = bf16_of(vv.y);
      lds16[(g4 * 4 + 2) * 200 + c] = bf16_of(vv.z);
      lds16[(g4 * 4 + 3) * 200 + c] = bf16_of(vv.w);
    }
  }

  bf16x8 wfrag[6][3];
#pragma unroll
  for (int ks = 0; ks < 6; ++ks)
#pragma unroll
    for (int nfi = 0; nfi < 3; ++nfi) {
      int nf = w * 3 + nfi;
      wfrag[ks][nfi] = ((const bf16x8*)wfr)[(nf * 6 + ks) * 64 + l];
    }

  __syncthreads();

  f32x4 acc[3][4];
#pragma unroll
  for (int a = 0; a < 3; ++a)
#pragma unroll
    for (int m = 0; m < 4; ++m) acc[a][m] = (f32x4){0.f, 0.f, 0.f, 0.f};

#pragma unroll
  for (int ks = 0; ks < 6; ++ks) {
    bf16x8 af[4];
#pragma unroll
    for (int mf = 0; mf < 4; ++mf)
      af[mf] = *(const bf16x8*)&lds[(mf * 16 + (l & 15)) * 100 + ks * 16 + (l >> 4) * 4];
#pragma unroll
    for (int nfi = 0; nfi < 3; ++nfi)
#pragma unroll
      for (int mf = 0; mf < 4; ++mf)
        acc[nfi][mf] = __builtin_amdgcn_mfma_f32_16x16x32_bf16(af[mf], wfrag[ks][nfi], acc[nfi][mf], 0, 0, 0);
  }

#pragma unroll
  for (int nfi = 0; nfi < 3; ++nfi) {
    int oc = (w * 3 + nfi) * 16 + (l & 15);
    float bs = bias[oc];
    if (outf) {
#pragma unroll
      for (int mf = 0; mf < 4; ++mf) {
        int pixb = n0 + mf * 16 + (l >> 4) * 4;
#pragma unroll
        for (int j = 0; j < 4; ++j)
          outf[(size_t)(pixb + j) * 192 + oc] = acc[nfi][mf][j] + bs;
      }
    } else {
      int pkh = oc >> 5, ch = oc & 31;
#pragma unroll
      for (int mf = 0; mf < 4; ++mf) {
        int pixb = n0 + mf * 16 + (l >> 4) * 4;
#pragma unroll
        for (int j = 0; j < 4; ++j)
          outh[((size_t)pkh * HW + pixb + j) * 32 + ch] = f16_of(acc[nfi][mf][j] + bs);
      }
    }
  }
}

// ---------------- Deformable attention (round-15 best): block = (b, half,
// head-pair, 32-pixel tile). 8 lanes per pixel = 2 corner-slots x 4 ch-quarters.
// kvp plane layout -> ~24KB L1-resident window. Records in-block in LDS.
__global__ __launch_bounds__(256, 4) void attn_kernel(
    const float* __restrict__ qp, const unsigned short* __restrict__ kvp,
    const float* __restrict__ offs, float* __restrict__ o_ws)
{
  __shared__ uint4 rec[2][2][9][32];   // [dgsel][clip][tap][pix]
  const int t = threadIdx.x;
  const int g = blockIdx.x & 7;          // (b, half) -> XCD-resident KV slab
  const int pos = blockIdx.x >> 3;       // 0..215
  const int b = g >> 1;
  const int half = g & 1;
  const int pk = pos / 36;
  const int tile = pos % 36;
  const int n_base = half * 1152 + tile * 32;

  // ---- in-block record computation: 1152 records, ~4.5 per thread
#pragma unroll
  for (int i = 0; i < 5; ++i) {
    int rid = t + i * 256;
    if (rid < 1152) {
      int rpix = rid & 31;
      int rest = rid >> 5;               // 0..35 = (dgsel, clip, tap)
      int rtap = rest % 9;
      int rq = rest / 9;                 // 0..3
      int rclip = rq & 1;
      int dgsel = rq >> 1;
      int rn = n_base + rpix;
      int rh = rn / WID, rw = rn % WID;
      int dg = pk + dgsel * 6;
      const float* ob = offs + ((size_t)(b * 2 + rclip) * 216 + (size_t)(dg * 9 + rtap) * 2) * HW + rn;
      float oy = ob[0];
      float ox = ob[HW];
      float py = (float)(rh - 1 + rtap / 3) + oy;
      float px = (float)(rw - 1 + rtap % 3) + ox;
      float y0f = floorf(py), x0f = floorf(px);
      int y0 = (int)y0f, x0 = (int)x0f;
      float wy1 = py - y0f, wx1 = px - x0f;
      float wy0 = 1.f - wy1, wx0 = 1.f - wx1;
      unsigned ip[2];
      float wv[4];
#pragma unroll
      for (int cy = 0; cy < 2; ++cy) {
        int yi = y0 + cy;
        float wyv = cy ? wy1 : wy0;
        int yc = yi < 0 ? 0 : (yi > 47 ? 47 : yi);
        bool vy = (unsigned)yi < 48u;
#pragma unroll
        for (int cx = 0; cx < 2; ++cx) {
          int xi = x0 + cx;
          float wxv = cx ? wx1 : wx0;
          int xc = xi < 0 ? 0 : (xi > 47 ? 47 : xi);
          bool vx = (unsigned)xi < 48u;
          float wgt = (vy && vx) ? wyv * wxv : 0.f;
          int ci = cy * 2 + cx;
          wv[ci] = wgt;
          ((unsigned short*)ip)[ci] = (unsigned short)(yc * WID + xc);
        }
      }
      uint4 rc;
      rc.x = ip[0];
      rc.y = ip[1];
      rc.z = __builtin_bit_cast(unsigned, pk_h2(wv[0], wv[1]));
      rc.w = __builtin_bit_cast(unsigned, pk_h2(wv[2], wv[3]));
      rec[dgsel][rclip][rtap][rpix] = rc;
    }
  }

  const int l8 = t & 7;
  const int csel = l8 >> 2;      // corner slot: 0 -> A/C, 1 -> B/D
  const int chq = l8 & 3;        // 8-channel quarter within the 32-ch head-pair
  const int pix = t >> 3;
  const int n = n_base + pix;

  // q: 8 channels for this lane's quarter
  half2v qh[4];
  {
    const float* qb = qp + ((size_t)b * HW + n) * 192 + pk * 32 + chq * 8;
    float4 v0 = *(const float4*)qb;
    float4 v1 = *(const float4*)(qb + 4);
    qh[0] = pk_h2(v0.x * 0.25f, v0.y * 0.25f);
    qh[1] = pk_h2(v0.z * 0.25f, v0.w * 0.25f);
    qh[2] = pk_h2(v1.x * 0.25f, v1.y * 0.25f);
    qh[3] = pk_h2(v1.z * 0.25f, v1.w * 0.25f);
  }

  __syncthreads();

  float sc[18];

  // ---- K phase: dense [HW][32] plane for (bc, k, pk); pure load+fdot body
#pragma unroll
  for (int c = 0; c < 2; ++c) {
    const unsigned short* kb = kvp + (((size_t)(b * 2 + c) * 2 + 0) * 6 + pk) * HW * 32 + chq * 8;
#pragma unroll
    for (int kk = 0; kk < 9; ++kk) {
      uint4 rc = rec[0][c][kk][pix];
      float s = 0.f;
#pragma unroll
      for (int r = 0; r < 2; ++r) {
        unsigned pr = r ? rc.y : rc.x;
        unsigned idx = csel ? (pr >> 16) : (pr & 0xFFFFu);
        half2v wp = __builtin_bit_cast(half2v, r ? rc.w : rc.z);
        _Float16 wh = csel ? wp.y : wp.x;
        uint4 u = *(const uint4*)(kb + (size_t)idx * 32);
        float d = __builtin_amdgcn_fdot2(qh[0], __builtin_bit_cast(half2v, u.x), 0.f, false);
        d = __builtin_amdgcn_fdot2(qh[1], __builtin_bit_cast(half2v, u.y), d, false);
        d = __builtin_amdgcn_fdot2(qh[2], __builtin_bit_cast(half2v, u.z), d, false);
        d = __builtin_amdgcn_fdot2(qh[3], __builtin_bit_cast(half2v, u.w), d, false);
        s += (float)wh * d;
      }
      sc[c * 9 + kk] = s;
    }
  }

  // ---- batched cross-lane reduction
#pragma unroll
  for (int j = 0; j < 18; ++j) sc[j] += __shfl_xor(sc[j], 1, 64);
#pragma unroll
  for (int j = 0; j < 18; ++j) sc[j] += __shfl_xor(sc[j], 4, 64);

  // ---- softmax over 18 taps (in registers, redundant per lane)
  {
    float m = -1e30f;
#pragma unroll
    for (int j = 0; j < 18; ++j) m = fmaxf(m, sc[j]);
    float sum = 0.f;
#pragma unroll
    for (int j = 0; j < 18; ++j) { float ev = __expf(sc[j] - m); sc[j] = ev; sum += ev; }
    float inv = 1.f / sum;
#pragma unroll
    for (int j = 0; j < 18; ++j) sc[j] *= inv;
  }

  // ---- V phase: dense [HW][32] plane for (bc, v, pk)
  float acc[8];
#pragma unroll
  for (int i = 0; i < 8; ++i) acc[i] = 0.f;
#pragma unroll
  for (int c = 0; c < 2; ++c) {
    const unsigned short* vb = kvp + (((size_t)(b * 2 + c) * 2 + 1) * 6 + pk) * HW * 32 + chq * 8;
#pragma unroll
    for (int kk = 0; kk < 9; ++kk) {
      uint4 rc = rec[1][c][kk][pix];
      float at = sc[c * 9 + kk];
#pragma unroll
      for (int r = 0; r < 2; ++r) {
        unsigned pr = r ? rc.y : rc.x;
        unsigned idx = csel ? (pr >> 16) : (pr & 0xFFFFu);
        half2v wp = __builtin_bit_cast(half2v, r ? rc.w : rc.z);
        _Float16 wh = csel ? wp.y : wp.x;
        uint4 u = *(const uint4*)(vb + (size_t)idx * 32);
        float cw = (float)wh * at;
        half2v v0 = __builtin_bit_cast(half2v, u.x);
        half2v v1 = __builtin_bit_cast(half2v, u.y);
        half2v v2 = __builtin_bit_cast(half2v, u.z);
        half2v v3 = __builtin_bit_cast(half2v, u.w);
        acc[0] += cw * (float)v0.x; acc[1] += cw * (float)v0.y;
        acc[2] += cw * (float)v1.x; acc[3] += cw * (float)v1.y;
        acc[4] += cw * (float)v2.x; acc[5] += cw * (float)v2.y;
        acc[6] += cw * (float)v3.x; acc[7] += cw * (float)v3.y;
      }
    }
  }

  // cross-corner-lane reduce (lane ^ 4 holds the other corner slot)
#pragma unroll
  for (int i = 0; i < 8; ++i) acc[i] += __shfl_xor(acc[i], 4, 64);

  if (csel == 0) {
    float* orow = o_ws + ((size_t)b * HW + n) * 192 + pk * 32 + chq * 8;
    float4 r0; r0.x = acc[0]; r0.y = acc[1]; r0.z = acc[2]; r0.w = acc[3];
    float4 r1; r1.x = acc[4]; r1.y = acc[5]; r1.z = acc[6]; r1.w = acc[7];
    *(float4*)orow = r0;
    *(float4*)(orow + 4) = r1;
  }
}

// ---------------- MLP via MFMA: one block per 16-pixel tile
__global__ __launch_bounds__(256) void mlp_mfma(
    const float* __restrict__ o_ws, const unsigned* __restrict__ wf,
    const float* __restrict__ b1, const float* __restrict__ b2,
    float* __restrict__ out)
{
  __shared__ unsigned ldsO[16 * 100];
  __shared__ unsigned ldsH[16 * 196];
  const unsigned* w1f = wf + 216 * 256;
  const unsigned* w2f = wf + 360 * 256;
  const int blk = blockIdx.x;
  const int b = blk / 144;
  const int n0 = (blk % 144) * 16;
  const int t = threadIdx.x;
  const int w = t >> 6, l = t & 63;

  for (int i = t; i < 16 * 96; i += 256) {
    int pix = i / 96, cp = i % 96;
    const float2 s = *(const float2*)(o_ws + ((size_t)(b * HW) + n0 + pix) * 192 + 2 * cp);
    ldsO[pix * 100 + cp] = pack_bf2(s.x, s.y);
  }
  __syncthreads();

  f32x4 acc1[6];
#pragma unroll
  for (int a = 0; a < 6; ++a) acc1[a] = (f32x4){0.f, 0.f, 0.f, 0.f};
#pragma unroll
  for (int ks = 0; ks < 6; ++ks) {
    bf16x8 af = *(const bf16x8*)&ldsO[(l & 15) * 100 + ks * 16 + (l >> 4) * 4];
#pragma unroll
    for (int nfi = 0; nfi < 6; ++nfi) {
      int nf = w * 6 + nfi;
      bf16x8 bfr = ((const bf16x8*)w1f)[(nf * 6 + ks) * 64 + l];
      acc1[nfi] = __builtin_amdgcn_mfma_f32_16x16x32_bf16(af, bfr, acc1[nfi], 0, 0, 0);
    }
  }

  {
    unsigned short* ldsHu = (unsigned short*)ldsH;
#pragma unroll
    for (int nfi = 0; nfi < 6; ++nfi) {
      int hc = (w * 6 + nfi) * 16 + (l & 15);
      float bs = b1[hc];
#pragma unroll
      for (int j = 0; j < 4; ++j) {
        int pix = (l >> 4) * 4 + j;
        float x = acc1[nfi][j] + bs;
        float gl = 0.5f * x * (1.f + erff(x * 0.70710678118654752f));
        ldsHu[pix * 392 + hc] = bf16_of(gl);
      }
    }
  }
  __syncthreads();

  f32x4 acc2[3];
#pragma unroll
  for (int a = 0; a < 3; ++a) acc2[a] = (f32x4){0.f, 0.f, 0.f, 0.f};
#pragma unroll
  for (int ks = 0; ks < 12; ++ks) {
    bf16x8 af = *(const bf16x8*)&ldsH[(l & 15) * 196 + ks * 16 + (l >> 4) * 4];
#pragma unroll
    for (int nfi = 0; nfi < 3; ++nfi) {
      int nf = w * 3 + nfi;
      bf16x8 bfr = ((const bf16x8*)w2f)[(nf * 12 + ks) * 64 + l];
      acc2[nfi] = __builtin_amdgcn_mfma_f32_16x16x32_bf16(af, bfr, acc2[nfi], 0, 0, 0);
    }
  }

#pragma unroll
  for (int nfi = 0; nfi < 3; ++nfi) {
    int oc = (w * 3 + nfi) * 16 + (l & 15);
    float bs = b2[oc];
#pragma unroll
    for (int j = 0; j < 4; ++j) {
      int pix = (l >> 4) * 4 + j;
      float res = o_ws[((size_t)(b * HW) + n0 + pix) * 192 + oc];
      out[((size_t)b * 192 + oc) * HW + n0 + pix] = acc2[nfi][j] + bs + res;
    }
  }
}

extern "C" void kernel_launch(void* const* d_in, const int* in_sizes, int n_in,
                              void* d_out, int out_size, void* d_ws, size_t ws_size,
                              hipStream_t stream) {
  const float* q = (const float*)d_in[0];
  const float* k = (const float*)d_in[1];
  const float* v = (const float*)d_in[2];
  const float* offset = (const float*)d_in[3];
  const float* wq = (const float*)d_in[4];
  const float* bq = (const float*)d_in[5];
  const float* wk = (const float*)d_in[6];
  const float* bk = (const float*)d_in[7];
  const float* wv = (const float*)d_in[8];
  const float* bv = (const float*)d_in[9];
  const float* w1 = (const float*)d_in[10];
  const float* b1 = (const float*)d_in[11];
  const float* w2 = (const float*)d_in[12];
  const float* b2 = (const float*)d_in[13];
  float* out = (float*)d_out;

  float* qp_t = (float*)d_ws;                                    // 4*2304*192 f32
  float* o_ws = qp_t + (size_t)4 * HW * 192;                     // 4*2304*192 f32
  unsigned short* kvp = (unsigned short*)(o_ws + (size_t)4 * HW * 192);  // 8*2*6*2304*32 u16
  unsigned* wfb = (unsigned*)(kvp + (size_t)8 * 2 * 6 * HW * 32);        // 504*256 u32

  prep_w<<<dim3(126), dim3(256), 0, stream>>>(wq, wk, wv, w1, w2, wfb);
  proj_mfma<<<dim3(36, 20), dim3(256), 0, stream>>>(q, k, v, wfb, bq, bk, bv, qp_t, kvp);
  attn_kernel<<<dim3(1728), dim3(256), 0, stream>>>(qp_t, kvp, offset, o_ws);
  mlp_mfma<<<dim3(576), dim3(256), 0, stream>>>(o_ws, wfb, b1, b2, out);
}